// Round 4
// baseline (495.404 us; speedup 1.0000x reference)
//
#include <hip/hip_runtime.h>

// Actor MLP, B=262144 rows, fp32. R3 post-mortem: one-thread-per-row needs 128
// live accumulators -> allocator parks z in AGPRs, occupancy pinned at 2
// waves/SIMD, latency-bound at 20% VALUBusy. Fix: 2 threads per row.
//   thread half t in {0,1}: phase1 computes groups [7t, 7t+7) -> s values to LDS
//   phase2: owns z-half = 64 floats (4 named f16v), c-loop over all 57 s values
//   phase3: 30 partial half-dots -> LDS exchange -> finalize 15 outputs each
// Per-thread state ~110 regs -> __launch_bounds__(256,4) -> 4 waves/SIMD.

typedef float f16v __attribute__((ext_vector_type(16)));
typedef float f4v  __attribute__((ext_vector_type(4)));

constexpr int NG = 14, GI = 9, SH = 16, SO = 4, FH = 128, AD = 15;
constexpr int RPB  = 128;   // rows per 256-thread block
constexpr int SSTR = 57;    // s_lds row stride (odd -> conflict-free)

__device__ __forceinline__ f4v load4u(const float* p) {
    f4v v; __builtin_memcpy(&v, p, 16); return v;   // 4B-aligned dwordx4
}

__global__ void w4t_kernel(const float* __restrict__ W4, float* __restrict__ W4T) {
    int t = blockIdx.x * 256 + threadIdx.x;
    if (t < FH * 2 * AD) {
        int j = t / (2 * AD), k = t % (2 * AD);   // W4[j][k]
        W4T[(size_t)k * FH + j] = W4[t];
    }
}

__global__ __launch_bounds__(256, 4) void actor_fused(
    const float* __restrict__ x,     // [B,126]
    const float* __restrict__ sale,  // [B,1]
    const float* __restrict__ W1,    // [9,16]
    const float* __restrict__ b1,    // [16]
    const float* __restrict__ W2,    // [16,4]
    const float* __restrict__ b2,    // [4]
    const float* __restrict__ W3,    // [57,128]
    const float* __restrict__ b3,    // [128]
    const float* __restrict__ W4T,   // [30,128] (transposed, in ws)
    const float* __restrict__ b4,    // [30]
    float* __restrict__ om, float* __restrict__ os, int B)
{
    // union: phase1/2 use [RPB][57] s-values; phase3 uses [2][RPB][30] partials
    __shared__ float smem[2 * RPB * 30];   // 7680 floats = 30.7 KB

    const int tid = threadIdx.x;
    const int t   = tid >> 7;        // row half (wave-uniform: waves 0,1 / 2,3)
    const int r   = tid & (RPB - 1); // row within block
    const int row = blockIdx.x * RPB + r;

    const f16v* w1v = (const f16v*)W1;
    const f4v*  w2v = (const f4v*)W2;
    const f16v  b1v = *(const f16v*)b1;
    const f4v   b2v = *(const f4v*)b2;
    float* srow = smem + r * SSTR;

    // ---- phase 1: shared block for groups [7t, 7t+7) ----
    const float* xr = x + (size_t)row * (NG * GI) + t * 7 * GI;
    #pragma unroll 1
    for (int g = 0; g < 7; ++g) {
        const float* xg = xr + g * GI;
        f4v ca = load4u(xg), cb = load4u(xg + 4);
        float cs = xg[8];

        f16v h = b1v;
        h += ca[0] * w1v[0]; h += ca[1] * w1v[1]; h += ca[2] * w1v[2];
        h += ca[3] * w1v[3]; h += cb[0] * w1v[4]; h += cb[1] * w1v[5];
        h += cb[2] * w1v[6]; h += cb[3] * w1v[7]; h += cs    * w1v[8];
        h = __builtin_elementwise_max(h, (f16v)0.f);

        f4v s = b2v;
        s += h[0]  * w2v[0];  s += h[1]  * w2v[1];  s += h[2]  * w2v[2];  s += h[3]  * w2v[3];
        s += h[4]  * w2v[4];  s += h[5]  * w2v[5];  s += h[6]  * w2v[6];  s += h[7]  * w2v[7];
        s += h[8]  * w2v[8];  s += h[9]  * w2v[9];  s += h[10] * w2v[10]; s += h[11] * w2v[11];
        s += h[12] * w2v[12]; s += h[13] * w2v[13]; s += h[14] * w2v[14]; s += h[15] * w2v[15];
        s = __builtin_elementwise_max(s, (f4v)0.f);

        int c = (t * 7 + g) * SO;
        srow[c + 0] = s[0]; srow[c + 1] = s[1];
        srow[c + 2] = s[2]; srow[c + 3] = s[3];
    }
    if (t) srow[56] = sale[row];
    __syncthreads();

    // ---- phase 2: z-half[64] = relu(b3h + sum_c s[c] * W3[c][64t..64t+63]) ----
    const float* b3h = b3 + t * 64;
    const float* w3h = W3 + t * 64;
    f16v z0 = *(const f16v*)(b3h +  0);
    f16v z1 = *(const f16v*)(b3h + 16);
    f16v z2 = *(const f16v*)(b3h + 32);
    f16v z3 = *(const f16v*)(b3h + 48);
    #pragma unroll 4
    for (int c = 0; c < 57; ++c) {
        float sv = srow[c];
        const f16v* wv = (const f16v*)(w3h + (size_t)c * FH);
        z0 += sv * wv[0]; z1 += sv * wv[1]; z2 += sv * wv[2]; z3 += sv * wv[3];
    }
    z0 = __builtin_elementwise_max(z0, (f16v)0.f);
    z1 = __builtin_elementwise_max(z1, (f16v)0.f);
    z2 = __builtin_elementwise_max(z2, (f16v)0.f);
    z3 = __builtin_elementwise_max(z3, (f16v)0.f);
    __syncthreads();   // all s reads done; smem reused for partials

    // ---- phase 3: partial half-dots out[k] over own 64 z-components ----
    float* prow = smem + (t * RPB + r) * 30;
    #pragma unroll 1
    for (int k = 0; k < 2 * AD; ++k) {
        const f16v* wv = (const f16v*)(W4T + (size_t)k * FH + t * 64);
        f16v a = z0 * wv[0];
        a += z1 * wv[1];
        a += z2 * wv[2];
        a += z3 * wv[3];
        float p0 = (a[0]  + a[1])  + (a[2]  + a[3]);
        float p1 = (a[4]  + a[5])  + (a[6]  + a[7]);
        float p2 = (a[8]  + a[9])  + (a[10] + a[11]);
        float p3 = (a[12] + a[13]) + (a[14] + a[15]);
        prow[k] = (p0 + p1) + (p2 + p3);
    }
    __syncthreads();

    // ---- finalize: t0 -> k=0..14 tanh -> om ; t1 -> k=15..29 exp -> os ----
    const float* pa = smem + r * 30;
    const float* pb = smem + (RPB + r) * 30;
    size_t ob = (size_t)row * AD;
    #pragma unroll 1
    for (int k = 0; k < AD; ++k) {
        int kk = t * AD + k;
        float v = pa[kk] + pb[kk] + b4[kk];
        if (t == 0) {
            float tc = fminf(fmaxf(v, -20.f), 20.f);
            float e = __expf(2.f * tc);
            om[ob + k] = (e - 1.f) / (e + 1.f);
        } else {
            os[ob + k] = __expf(v);
        }
    }
}

extern "C" void kernel_launch(void* const* d_in, const int* in_sizes, int n_in,
                              void* d_out, int out_size, void* d_ws, size_t ws_size,
                              hipStream_t stream) {
    const float* x    = (const float*)d_in[0];
    const float* sale = (const float*)d_in[1];
    const float* W1   = (const float*)d_in[2];
    const float* b1   = (const float*)d_in[3];
    const float* W2   = (const float*)d_in[4];
    const float* b2   = (const float*)d_in[5];
    const float* W3   = (const float*)d_in[6];
    const float* b3   = (const float*)d_in[7];
    const float* W4   = (const float*)d_in[8];
    const float* b4   = (const float*)d_in[9];

    int B = in_sizes[1];                       // sale_predictions is [B,1]
    float* om = (float*)d_out;                 // action_mean flat [B*15]
    float* os = om + (size_t)B * AD;           // action_std  flat [B*15]
    float* W4T = (float*)d_ws;                 // [30,128]

    w4t_kernel<<<(FH * 2 * AD + 255) / 256, 256, 0, stream>>>(W4, W4T);
    int grid = B / RPB;                        // B = 262144 -> 2048 blocks
    actor_fused<<<grid, 256, 0, stream>>>(x, sale, W1, b1, W2, b2, W3, b3,
                                          W4T, b4, om, os, B);
}

// Round 5
// 141.312 us; speedup vs baseline: 3.5058x; 3.5058x over previous
//
#include <hip/hip_runtime.h>

// Actor MLP, B=262144 rows, fp32. 2 threads per row, z split 64+64.
// R4 post-mortem: t = tid>>7 is wave-uniform in fact but divergence analysis
// can't prove it -> W3/W4T reads became per-lane VMEM -> operand flood ->
// spill catastrophe (WRITE_SIZE 310MB). Fix: readfirstlane the half-offsets so
// all weight reads are s_load (SGPR, scalar pipe); VALU does pure v_fmac with
// one SGPR source. Partials stride 31 (odd) kills the 4-way bank conflict.

typedef float f16v __attribute__((ext_vector_type(16)));
typedef float f4v  __attribute__((ext_vector_type(4)));

constexpr int NG = 14, GI = 9, SH = 16, SO = 4, FH = 128, AD = 15;
constexpr int RPB  = 128;   // rows per 256-thread block
constexpr int SSTR = 57;    // s region stride (odd -> conflict-free)
constexpr int PSTR = 31;    // partials stride (odd -> conflict-free)

__device__ __forceinline__ f4v load4u(const float* p) {
    f4v v; __builtin_memcpy(&v, p, 16); return v;   // 4B-aligned dwordx4
}

__global__ void w4t_kernel(const float* __restrict__ W4, float* __restrict__ W4T) {
    int t = blockIdx.x * 256 + threadIdx.x;
    if (t < FH * 2 * AD) {
        int j = t / (2 * AD), k = t % (2 * AD);   // W4[j][k]
        W4T[(size_t)k * FH + j] = W4[t];
    }
}

__global__ __launch_bounds__(256, 4) void actor_fused(
    const float* __restrict__ x,     // [B,126]
    const float* __restrict__ sale,  // [B,1]
    const float* __restrict__ W1,    // [9,16]
    const float* __restrict__ b1,    // [16]
    const float* __restrict__ W2,    // [16,4]
    const float* __restrict__ b2,    // [4]
    const float* __restrict__ W3,    // [57,128]
    const float* __restrict__ b3,    // [128]
    const float* __restrict__ W4T,   // [30,128] (transposed, in ws)
    const float* __restrict__ b4,    // [30]
    float* __restrict__ om, float* __restrict__ os, int B)
{
    // union: phase1/2 = s values [RPB][57]; phase3 = partials [2][RPB][31]
    __shared__ float smem[2 * RPB * PSTR];   // 7936 floats = 31.7 KB

    const int tid = threadIdx.x;
    const int t   = tid >> 7;        // row half; waves {0,1}->0, {2,3}->1
    const int r   = tid & (RPB - 1);
    const int row = blockIdx.x * RPB + r;

    // wave-uniform offsets, forced scalar so weight reads become s_load
    const unsigned toff = __builtin_amdgcn_readfirstlane((unsigned)(t * 64));
    const unsigned gbase = __builtin_amdgcn_readfirstlane((unsigned)(t * 7));

    const f16v* w1v = (const f16v*)W1;
    const f4v*  w2v = (const f4v*)W2;
    const f16v  b1v = *(const f16v*)b1;
    const f4v   b2v = *(const f4v*)b2;
    float* srow = smem + r * SSTR;

    // ---- phase 1: shared block for 7 groups [gbase, gbase+7) ----
    const float* xr = x + (size_t)row * (NG * GI) + gbase * GI;
    #pragma unroll 1
    for (int g = 0; g < 7; ++g) {
        const float* xg = xr + g * GI;
        f4v ca = load4u(xg), cb = load4u(xg + 4);
        float cs = xg[8];

        f16v h = b1v;
        h += ca[0] * w1v[0]; h += ca[1] * w1v[1]; h += ca[2] * w1v[2];
        h += ca[3] * w1v[3]; h += cb[0] * w1v[4]; h += cb[1] * w1v[5];
        h += cb[2] * w1v[6]; h += cb[3] * w1v[7]; h += cs    * w1v[8];
        h = __builtin_elementwise_max(h, (f16v)0.f);

        f4v s = b2v;
        s += h[0]  * w2v[0];  s += h[1]  * w2v[1];  s += h[2]  * w2v[2];  s += h[3]  * w2v[3];
        s += h[4]  * w2v[4];  s += h[5]  * w2v[5];  s += h[6]  * w2v[6];  s += h[7]  * w2v[7];
        s += h[8]  * w2v[8];  s += h[9]  * w2v[9];  s += h[10] * w2v[10]; s += h[11] * w2v[11];
        s += h[12] * w2v[12]; s += h[13] * w2v[13]; s += h[14] * w2v[14]; s += h[15] * w2v[15];
        s = __builtin_elementwise_max(s, (f4v)0.f);

        int c = (gbase + g) * SO;
        srow[c + 0] = s[0]; srow[c + 1] = s[1];
        srow[c + 2] = s[2]; srow[c + 3] = s[3];
    }
    if (t) srow[56] = sale[row];
    __syncthreads();

    // ---- phase 2: z-half[64] = relu(b3h + sum_c s[c]*W3[c][toff..toff+64)) ----
    const float* b3h = b3 + toff;   // uniform -> s_load
    const float* w3h = W3 + toff;   // uniform -> s_load
    f16v z0 = *(const f16v*)(b3h +  0);
    f16v z1 = *(const f16v*)(b3h + 16);
    f16v z2 = *(const f16v*)(b3h + 32);
    f16v z3 = *(const f16v*)(b3h + 48);
    #pragma unroll 1
    for (int c = 0; c < 57; ++c) {
        float sv = srow[c];
        const f16v* wv = (const f16v*)(w3h + (size_t)c * FH);
        z0 += sv * wv[0]; z1 += sv * wv[1]; z2 += sv * wv[2]; z3 += sv * wv[3];
    }
    z0 = __builtin_elementwise_max(z0, (f16v)0.f);
    z1 = __builtin_elementwise_max(z1, (f16v)0.f);
    z2 = __builtin_elementwise_max(z2, (f16v)0.f);
    z3 = __builtin_elementwise_max(z3, (f16v)0.f);
    __syncthreads();   // all s reads done; smem reused for partials

    // ---- phase 3: partial half-dots for all 30 outputs over own 64 z ----
    float* prow = smem + (t * RPB + r) * PSTR;
    #pragma unroll 1
    for (int k = 0; k < 2 * AD; ++k) {
        const f16v* wv = (const f16v*)(W4T + (size_t)k * FH + toff);  // uniform
        f16v a = z0 * wv[0];
        a += z1 * wv[1];
        a += z2 * wv[2];
        a += z3 * wv[3];
        float p0 = (a[0]  + a[1])  + (a[2]  + a[3]);
        float p1 = (a[4]  + a[5])  + (a[6]  + a[7]);
        float p2 = (a[8]  + a[9])  + (a[10] + a[11]);
        float p3 = (a[12] + a[13]) + (a[14] + a[15]);
        prow[k] = (p0 + p1) + (p2 + p3);
    }
    __syncthreads();

    // ---- finalize: t=0 -> tanh -> om[k<15]; t=1 -> exp -> os[k-15] ----
    const float* pa = smem + r * PSTR;
    const float* pb = smem + (RPB + r) * PSTR;
    size_t ob = (size_t)row * AD;
    #pragma unroll 1
    for (int k = 0; k < AD; ++k) {
        int kk = t * AD + k;
        float v = pa[kk] + pb[kk] + b4[kk];
        if (t == 0) {
            float tc = fminf(fmaxf(v, -20.f), 20.f);
            float e = __expf(2.f * tc);
            om[ob + k] = (e - 1.f) / (e + 1.f);
        } else {
            os[ob + k] = __expf(v);
        }
    }
}

extern "C" void kernel_launch(void* const* d_in, const int* in_sizes, int n_in,
                              void* d_out, int out_size, void* d_ws, size_t ws_size,
                              hipStream_t stream) {
    const float* x    = (const float*)d_in[0];
    const float* sale = (const float*)d_in[1];
    const float* W1   = (const float*)d_in[2];
    const float* b1   = (const float*)d_in[3];
    const float* W2   = (const float*)d_in[4];
    const float* b2   = (const float*)d_in[5];
    const float* W3   = (const float*)d_in[6];
    const float* b3   = (const float*)d_in[7];
    const float* W4   = (const float*)d_in[8];
    const float* b4   = (const float*)d_in[9];

    int B = in_sizes[1];                       // sale_predictions is [B,1]
    float* om = (float*)d_out;                 // action_mean flat [B*15]
    float* os = om + (size_t)B * AD;           // action_std  flat [B*15]
    float* W4T = (float*)d_ws;                 // [30,128]

    w4t_kernel<<<(FH * 2 * AD + 255) / 256, 256, 0, stream>>>(W4, W4T);
    int grid = B / RPB;                        // 2048 blocks
    actor_fused<<<grid, 256, 0, stream>>>(x, sale, W1, b1, W2, b2, W3, b3,
                                          W4T, b4, om, os, B);
}